// Round 1
// baseline (219.011 us; speedup 1.0000x reference)
//
#include <hip/hip_runtime.h>
#include <hip/hip_bf16.h>
#include <math.h>

// MoE top-2 of 8 experts. B=8, C=512, H*W=1024, Dh=1024, E=8.
// Strategy: exact fp32 gate; bf16 MFMA for the two selected experts per sample.
// Workspace layout (bytes):
//   [0, 16384)              mean fp32 [B*C]
//   [16384, 16448)          scale fp32 [B*2]  (= topk_w * k[b])
//   [16448, 16512)          topk idx int [B*2]
//   [32768, +8MB)           xT  bf16 [B][1024][512]   (x transposed, K=c contiguous)
//   [+8MB, +16MB)           W1t bf16 [E][1024][512]   (W1 transposed, [d][c])
//   [+16MB, +24MB)          W2t bf16 [E][512][1024]   (W2 transposed, [c][d])
//   [+24MB, +56MB)          hT  bf16 [B][1024][2048]  (gelu(h)*scale, both experts K-concat)
// Total ~56.03 MB.

typedef __bf16 bf16_t;
typedef __attribute__((ext_vector_type(8))) __bf16 bf16x8;
typedef __attribute__((ext_vector_type(4))) __bf16 bf16x4;
typedef __attribute__((ext_vector_type(4))) float f32x4;

#define GLDS(g, l) __builtin_amdgcn_global_load_lds(                      \
    (const __attribute__((address_space(1))) void*)(const void*)(g),       \
    (__attribute__((address_space(3))) void*)(void*)(l), 16, 0, 0)

__device__ __forceinline__ float gelu_exact(float x) {
    return 0.5f * x * (1.0f + erff(x * 0.70710678118654752f));
}

// ---------- 1. per-(b,c) mean over HW=1024 ----------
__global__ void mean_kernel(const float* __restrict__ x, float* __restrict__ mean) {
    int bid = blockIdx.x;           // b*512 + c
    int tid = threadIdx.x;          // 256
    float4 v = ((const float4*)(x + (size_t)bid * 1024))[tid];
    float s = v.x + v.y + v.z + v.w;
    #pragma unroll
    for (int off = 32; off > 0; off >>= 1) s += __shfl_down(s, off, 64);
    __shared__ float partial[4];
    if ((tid & 63) == 0) partial[tid >> 6] = s;
    __syncthreads();
    if (tid == 0)
        mean[bid] = (partial[0] + partial[1] + partial[2] + partial[3]) * (1.0f / 1024.0f);
}

// ---------- 2. gate: logits -> softmax -> top-2 -> scale = w * k[b] ----------
__global__ void gate_kernel(const float* __restrict__ mean, const float* __restrict__ Wg,
                            const float* __restrict__ bg, const float* __restrict__ kmod,
                            int* __restrict__ tidx, float* __restrict__ scale) {
    int t = threadIdx.x;            // 64 threads: (b,e) = (t>>3, t&7)
    int b = t >> 3, e = t & 7;
    float acc = bg[e];
    for (int c = 0; c < 512; ++c)
        acc += mean[b * 512 + c] * Wg[c * 8 + e];
    // softmax within groups of 8 lanes (fp32, max-subtracted, matches jax)
    float mx = acc;
    #pragma unroll
    for (int m = 4; m; m >>= 1) mx = fmaxf(mx, __shfl_xor(mx, m, 8));
    float ex = expf(acc - mx);
    float sum = ex;
    #pragma unroll
    for (int m = 4; m; m >>= 1) sum += __shfl_xor(sum, m, 8);
    float w = ex / sum;
    __shared__ float wsm[64];
    wsm[t] = w;
    __syncthreads();
    if (e == 0) {
        float kb = kmod[b];
        float best = -1.f; int i0 = 0;
        for (int j = 0; j < 8; ++j) { float v = wsm[b * 8 + j]; if (v > best) { best = v; i0 = j; } }
        float best2 = -1.f; int i1 = 0;
        for (int j = 0; j < 8; ++j) { if (j == i0) continue; float v = wsm[b * 8 + j]; if (v > best2) { best2 = v; i1 = j; } }
        tidx[b * 2]  = i0;  tidx[b * 2 + 1]  = i1;
        scale[b * 2] = best * kb; scale[b * 2 + 1] = best2 * kb;
    }
}

// ---------- 3. batched transpose + fp32->bf16: src[bz][R][Cols] -> dst[bz][Cols][R] ----------
__global__ void transpose_cvt(const float* __restrict__ src, bf16_t* __restrict__ dst,
                              int R, int Cols) {
    int bz = blockIdx.z;
    int c0 = blockIdx.x * 32, r0 = blockIdx.y * 32;
    const float* s = src + (size_t)bz * R * Cols;
    bf16_t* d = dst + (size_t)bz * R * Cols;
    __shared__ float tile[32][33];
    int tid = threadIdx.x;          // 256
    int lr = tid >> 3, lc = (tid & 7) * 4;
    float4 v = *(const float4*)(s + (size_t)(r0 + lr) * Cols + c0 + lc);
    tile[lr][lc + 0] = v.x; tile[lr][lc + 1] = v.y;
    tile[lr][lc + 2] = v.z; tile[lr][lc + 3] = v.w;
    __syncthreads();
    bf16x4 o = { (bf16_t)tile[lc + 0][lr], (bf16_t)tile[lc + 1][lr],
                 (bf16_t)tile[lc + 2][lr], (bf16_t)tile[lc + 3][lr] };
    *(bf16x4*)(d + (size_t)(c0 + lr) * R + r0 + lc) = o;
}

// ---------- 4. GEMM1: h[d][hw] = gelu(sum_c W1[c][d]*x[c][hw] + b1[d]) * s, store hT[hw][slot*1024+d] bf16
// m97 structure: 128x128 tile, BK=32, 4 waves in 2x2, global_load_lds width 16.
__global__ __launch_bounds__(256) void gemm1_kernel(
    const bf16_t* __restrict__ W1t, const bf16_t* __restrict__ xT,
    const float* __restrict__ b1, const int* __restrict__ tidx,
    const float* __restrict__ scale, bf16_t* __restrict__ hT) {
    __shared__ alignas(16) bf16_t lA[128 * 32];
    __shared__ alignas(16) bf16_t lB[128 * 32];
    int bid = blockIdx.x;
    int pair = bid >> 6, tile = bid & 63;   // pair = b*2+slot
    int b = pair >> 1, slot = pair & 1;
    int e = tidx[pair];
    float s = scale[pair];
    int d0 = (tile >> 3) * 128, n0 = (tile & 7) * 128;
    int tid = threadIdx.x;
    int lane = tid & 63, wave = tid >> 6;
    int wm = (wave & 1) * 64, wn = (wave >> 1) * 64;
    int lrow = lane & 15, quad = lane >> 4;

    const bf16_t* gA = W1t + (size_t)e * (1024 * 512) + (size_t)d0 * 512;
    const bf16_t* gB = xT  + (size_t)b * (1024 * 512) + (size_t)n0 * 512;

    f32x4 zero = {0.f, 0.f, 0.f, 0.f};
    f32x4 acc[4][4];
    #pragma unroll
    for (int i = 0; i < 4; ++i)
        #pragma unroll
        for (int j = 0; j < 4; ++j) acc[i][j] = zero;

    for (int k0 = 0; k0 < 512; k0 += 32) {
        #pragma unroll
        for (int i = 0; i < 2; ++i) {
            int idx = i * 256 + tid;
            int row = idx >> 2;
            int p8 = (idx & 3) * 8;
            GLDS(gA + (size_t)row * 512 + k0 + p8, lA + idx * 8);
            GLDS(gB + (size_t)row * 512 + k0 + p8, lB + idx * 8);
        }
        __syncthreads();
        bf16x8 af[4], bf[4];
        #pragma unroll
        for (int i = 0; i < 4; ++i) {
            af[i] = *(const bf16x8*)&lA[(wm + i * 16 + lrow) * 32 + quad * 8];
            bf[i] = *(const bf16x8*)&lB[(wn + i * 16 + lrow) * 32 + quad * 8];
        }
        #pragma unroll
        for (int i = 0; i < 4; ++i)
            #pragma unroll
            for (int j = 0; j < 4; ++j)
                acc[i][j] = __builtin_amdgcn_mfma_f32_16x16x32_bf16(af[i], bf[j], acc[i][j], 0, 0, 0);
        __syncthreads();
    }

    bf16_t* hrow = hT + (size_t)b * (1024 * 2048) + slot * 1024;
    #pragma unroll
    for (int i = 0; i < 4; ++i) {
        int dbase = d0 + wm + i * 16 + quad * 4;
        float4 bb = *(const float4*)(b1 + e * 1024 + dbase);
        #pragma unroll
        for (int j = 0; j < 4; ++j) {
            int hw = n0 + wn + j * 16 + lrow;
            f32x4 a = acc[i][j];
            bf16x4 o = { (bf16_t)(gelu_exact(a[0] + bb.x) * s),
                         (bf16_t)(gelu_exact(a[1] + bb.y) * s),
                         (bf16_t)(gelu_exact(a[2] + bb.z) * s),
                         (bf16_t)(gelu_exact(a[3] + bb.w) * s) };
            *(bf16x4*)(hrow + (size_t)hw * 2048 + dbase) = o;
        }
    }
}

// ---------- 5. GEMM2 over K=2048 (both experts concat) + residual + scaled b2 bias ----------
__global__ __launch_bounds__(256) void gemm2_kernel(
    const bf16_t* __restrict__ W2t, const bf16_t* __restrict__ hT,
    const float* __restrict__ b2, const int* __restrict__ tidx,
    const float* __restrict__ scale, const float* __restrict__ x,
    float* __restrict__ out) {
    __shared__ alignas(16) bf16_t lA[128 * 32];
    __shared__ alignas(16) bf16_t lB[128 * 32];
    int bid = blockIdx.x;
    int b = bid >> 5, tile = bid & 31;
    int c0 = (tile >> 3) * 128, n0 = (tile & 7) * 128;
    int e0 = tidx[b * 2], e1 = tidx[b * 2 + 1];
    float s0 = scale[b * 2], s1 = scale[b * 2 + 1];
    int tid = threadIdx.x;
    int lane = tid & 63, wave = tid >> 6;
    int wm = (wave & 1) * 64, wn = (wave >> 1) * 64;
    int lrow = lane & 15, quad = lane >> 4;

    const bf16_t* gB = hT + (size_t)b * (1024 * 2048) + (size_t)n0 * 2048;

    f32x4 zero = {0.f, 0.f, 0.f, 0.f};
    f32x4 acc[4][4];
    #pragma unroll
    for (int i = 0; i < 4; ++i)
        #pragma unroll
        for (int j = 0; j < 4; ++j) acc[i][j] = zero;

    for (int k0 = 0; k0 < 2048; k0 += 32) {
        int e = (k0 < 1024) ? e0 : e1;
        int kk = k0 & 1023;
        const bf16_t* gA = W2t + (size_t)e * (512 * 1024) + (size_t)c0 * 1024 + kk;
        #pragma unroll
        for (int i = 0; i < 2; ++i) {
            int idx = i * 256 + tid;
            int row = idx >> 2;
            int p8 = (idx & 3) * 8;
            GLDS(gA + (size_t)row * 1024 + p8, lA + idx * 8);
            GLDS(gB + (size_t)row * 2048 + k0 + p8, lB + idx * 8);
        }
        __syncthreads();
        bf16x8 af[4], bf[4];
        #pragma unroll
        for (int i = 0; i < 4; ++i) {
            af[i] = *(const bf16x8*)&lA[(wm + i * 16 + lrow) * 32 + quad * 8];
            bf[i] = *(const bf16x8*)&lB[(wn + i * 16 + lrow) * 32 + quad * 8];
        }
        #pragma unroll
        for (int i = 0; i < 4; ++i)
            #pragma unroll
            for (int j = 0; j < 4; ++j)
                acc[i][j] = __builtin_amdgcn_mfma_f32_16x16x32_bf16(af[i], bf[j], acc[i][j], 0, 0, 0);
        __syncthreads();
    }

    #pragma unroll
    for (int i = 0; i < 4; ++i) {
        int cbase = c0 + wm + i * 16 + quad * 4;
        float4 bA = *(const float4*)(b2 + e0 * 512 + cbase);
        float4 bB = *(const float4*)(b2 + e1 * 512 + cbase);
        float bias[4] = { s0 * bA.x + s1 * bB.x, s0 * bA.y + s1 * bB.y,
                          s0 * bA.z + s1 * bB.z, s0 * bA.w + s1 * bB.w };
        #pragma unroll
        for (int j = 0; j < 4; ++j) {
            int hw = n0 + wn + j * 16 + lrow;
            #pragma unroll
            for (int r = 0; r < 4; ++r) {
                size_t o = ((size_t)(b * 512 + cbase + r)) * 1024 + hw;
                out[o] = x[o] + acc[i][j][r] + bias[r];
            }
        }
    }
}

extern "C" void kernel_launch(void* const* d_in, const int* in_sizes, int n_in,
                              void* d_out, int out_size, void* d_ws, size_t ws_size,
                              hipStream_t stream) {
    const float* x    = (const float*)d_in[0];
    const float* kmod = (const float*)d_in[1];
    const float* Wg   = (const float*)d_in[2];
    const float* bg   = (const float*)d_in[3];
    const float* W1   = (const float*)d_in[4];
    const float* b1   = (const float*)d_in[5];
    const float* W2   = (const float*)d_in[6];
    const float* b2   = (const float*)d_in[7];
    float* out = (float*)d_out;

    char* ws = (char*)d_ws;
    float* mean  = (float*)(ws);
    float* scale = (float*)(ws + 16384);
    int*   tidx  = (int*)(ws + 16448);
    bf16_t* xT   = (bf16_t*)(ws + 32768);
    bf16_t* W1t  = (bf16_t*)(ws + 32768 + (size_t)8388608);
    bf16_t* W2t  = (bf16_t*)(ws + 32768 + (size_t)2 * 8388608);
    bf16_t* hT   = (bf16_t*)(ws + 32768 + (size_t)3 * 8388608);

    mean_kernel<<<4096, 256, 0, stream>>>(x, mean);
    gate_kernel<<<1, 64, 0, stream>>>(mean, Wg, bg, kmod, tidx, scale);
    transpose_cvt<<<dim3(32, 16, 8), 256, 0, stream>>>(x,  xT,  512, 1024);
    transpose_cvt<<<dim3(32, 16, 8), 256, 0, stream>>>(W1, W1t, 512, 1024);
    transpose_cvt<<<dim3(16, 32, 8), 256, 0, stream>>>(W2, W2t, 1024, 512);
    gemm1_kernel<<<1024, 256, 0, stream>>>(W1t, xT, b1, tidx, scale, hT);
    gemm2_kernel<<<256, 256, 0, stream>>>(W2t, hT, b2, tidx, scale, x, out);
}

// Round 2
// 177.928 us; speedup vs baseline: 1.2309x; 1.2309x over previous
//
#include <hip/hip_runtime.h>
#include <hip/hip_bf16.h>
#include <math.h>

// MoE top-2 of 8 experts. B=8, C=512, HW=1024, Dh=1024, E=8. fp32 in/out.
// R2: single-barrier dbuf K-loops, 1024-block grids for both GEMMs,
// LDS-transposed coalesced hT epilogue, poly-erf gelu, fused transposes+mean.
// Workspace:
//   [0,16K)      msum fp32 [8*512] (atomic-accumulated channel sums; memset 0)
//   [16384..)    scale fp32 [16], tidx int [16]
//   [32768,+8M)  xT  bf16 [8][1024 hw][512 c]
//   [+8M,+16M)   W1t bf16 [8][1024 d][512 c]
//   [+16M,+24M)  W2t bf16 [8][512 c][1024 d]
//   [+24M,+56M)  hT  bf16 [8][1024 hw][2048 slotd]  (gelu(h)*w*k, experts K-concat)

typedef __bf16 bf16_t;
typedef __attribute__((ext_vector_type(8))) __bf16 bf16x8;
typedef __attribute__((ext_vector_type(4))) __bf16 bf16x4;
typedef __attribute__((ext_vector_type(4))) float f32x4;

#define GLDS(g, l) __builtin_amdgcn_global_load_lds(                      \
    (const __attribute__((address_space(1))) void*)(const void*)(g),       \
    (__attribute__((address_space(3))) void*)(void*)(l), 16, 0, 0)

// erf via Abramowitz-Stegun 7.1.26 (|err|<=1.5e-7, far below bf16 noise floor)
__device__ __forceinline__ float gelu_fast(float x) {
    float z = x * 0.70710678118654752f;
    float az = fabsf(z);
    float t = 1.0f / (1.0f + 0.3275911f * az);
    float p = ((((1.061405429f * t - 1.453152027f) * t + 1.421413741f) * t
                - 0.284496736f) * t + 0.254829592f) * t;
    float e = __expf(-az * az);
    float er = copysignf(1.0f - p * e, z);
    return 0.5f * x * (1.0f + er);
}

// ---------- 1. fused transpose+cvt for x/W1/W2, + channel sums for the gate ----------
__global__ void transpose_cvt_all(const float* __restrict__ x, const float* __restrict__ W1,
                                  const float* __restrict__ W2, bf16_t* __restrict__ xT,
                                  bf16_t* __restrict__ W1t, bf16_t* __restrict__ W2t,
                                  float* __restrict__ msum) {
    int id = blockIdx.x;
    const float* src; bf16_t* dst; int R, Cols, csh; bool dm = false;
    if (id < 4096)      { src = x;  dst = xT;  R = 512;  Cols = 1024; csh = 5; dm = true; }
    else if (id < 8192) { id -= 4096; src = W1; dst = W1t; R = 512;  Cols = 1024; csh = 5; }
    else                { id -= 8192; src = W2; dst = W2t; R = 1024; Cols = 512; csh = 4; }
    const int bz = id >> 9, t = id & 511;
    const int c0 = (t & ((1 << csh) - 1)) * 32, r0 = (t >> csh) * 32;
    const float* s = src + (size_t)bz * R * Cols;
    bf16_t* d = dst + (size_t)bz * R * Cols;
    __shared__ float tile[32][33];
    const int tid = threadIdx.x;
    const int lr = tid >> 3, lc = (tid & 7) * 4;
    float4 v = *(const float4*)(s + (size_t)(r0 + lr) * Cols + c0 + lc);
    tile[lr][lc + 0] = v.x; tile[lr][lc + 1] = v.y;
    tile[lr][lc + 2] = v.z; tile[lr][lc + 3] = v.w;
    if (dm) {  // partial hw-sum per channel row (feeds gate mean)
        float ps = v.x + v.y + v.z + v.w;
        ps += __shfl_down(ps, 4, 8);
        ps += __shfl_down(ps, 2, 8);
        ps += __shfl_down(ps, 1, 8);
        if ((tid & 7) == 0) atomicAdd(&msum[bz * 512 + r0 + lr], ps);
    }
    __syncthreads();
    bf16x4 o = { (bf16_t)tile[lc + 0][lr], (bf16_t)tile[lc + 1][lr],
                 (bf16_t)tile[lc + 2][lr], (bf16_t)tile[lc + 3][lr] };
    *(bf16x4*)(d + (size_t)(c0 + lr) * R + r0 + lc) = o;
}

// ---------- 2. gate: logits -> softmax -> top2 -> scale = w * k[b]; 1 wave per sample ----------
__global__ void gate_kernel(const float* __restrict__ msum, const float* __restrict__ Wg,
                            const float* __restrict__ bg, const float* __restrict__ kmod,
                            int* __restrict__ tidx, float* __restrict__ scale) {
    const int tid = threadIdx.x;           // 512 threads = 8 waves, wave b
    const int b = tid >> 6, l = tid & 63;
    float a[8] = {0.f, 0.f, 0.f, 0.f, 0.f, 0.f, 0.f, 0.f};
    for (int c = l; c < 512; c += 64) {
        float m = msum[b * 512 + c];
        #pragma unroll
        for (int e = 0; e < 8; ++e) a[e] += m * Wg[c * 8 + e];
    }
    #pragma unroll
    for (int e = 0; e < 8; ++e)
        #pragma unroll
        for (int off = 32; off; off >>= 1) a[e] += __shfl_xor(a[e], off, 64);
    if (l == 0) {
        float lg[8], mx = -1e30f;
        #pragma unroll
        for (int e = 0; e < 8; ++e) { lg[e] = a[e] * (1.0f / 1024.0f) + bg[e]; mx = fmaxf(mx, lg[e]); }
        float sum = 0.f;
        #pragma unroll
        for (int e = 0; e < 8; ++e) { lg[e] = expf(lg[e] - mx); sum += lg[e]; }
        float inv = 1.0f / sum;
        float best = -1.f; int i0 = 0;
        for (int j = 0; j < 8; ++j) { float w = lg[j] * inv; if (w > best) { best = w; i0 = j; } }
        float best2 = -1.f; int i1 = 0;
        for (int j = 0; j < 8; ++j) { if (j == i0) continue; float w = lg[j] * inv; if (w > best2) { best2 = w; i1 = j; } }
        float kb = kmod[b];
        tidx[b * 2] = i0; tidx[b * 2 + 1] = i1;
        scale[b * 2] = best * kb; scale[b * 2 + 1] = best2 * kb;
    }
}

// ---------- 3. GEMM1: hT[b][hw][slot*1024+d] = bf16(gelu(W1t[e] @ xT[b] + b1)*scale)
// 128x128 tile, BK=32, single-barrier dbuf (prefetch next stage before compute),
// LDS-transposed epilogue for 128B-contiguous hT writes.
__global__ __launch_bounds__(256, 4) void gemm1_kernel(
    const bf16_t* __restrict__ W1t, const bf16_t* __restrict__ xT,
    const float* __restrict__ b1, const int* __restrict__ tidx,
    const float* __restrict__ scale, bf16_t* __restrict__ hT) {
    __shared__ bf16_t smem[16384];   // 32KB: A stages @0/4096, B stages @8192/12288
    const int bid = blockIdx.x;
    const int pair = bid >> 6, rem = bid & 63;
    const int b = pair >> 1, slot = pair & 1;
    const int e = tidx[pair];
    const float s = scale[pair];
    const int d0 = (rem >> 3) * 128, n0 = (rem & 7) * 128;
    const int tid = threadIdx.x;
    const int lane = tid & 63, wave = tid >> 6;
    const int wm = (wave & 1) * 64, wn = (wave >> 1) * 64;
    const int lrow = lane & 15, quad = lane >> 4;

    const bf16_t* gA = W1t + (size_t)e * 524288 + (size_t)d0 * 512;
    const bf16_t* gB = xT + (size_t)b * 524288 + (size_t)n0 * 512;
    const int r0s = tid >> 2, kcs = (tid & 3) * 8;   // chunk g=tid -> rows 0..63
                                                     // chunk g=256+tid -> rows 64..127
    f32x4 acc[4][4];
    #pragma unroll
    for (int i = 0; i < 4; ++i)
        #pragma unroll
        for (int j = 0; j < 4; ++j) acc[i][j] = (f32x4){0.f, 0.f, 0.f, 0.f};

    // prologue: stage 0 @ k=0
    GLDS(gA + r0s * 512 + kcs, smem + tid * 8);
    GLDS(gA + (64 + r0s) * 512 + kcs, smem + (256 + tid) * 8);
    GLDS(gB + r0s * 512 + kcs, smem + 8192 + tid * 8);
    GLDS(gB + (64 + r0s) * 512 + kcs, smem + 8192 + (256 + tid) * 8);
    __syncthreads();

    for (int it = 0; it < 16; ++it) {
        const int cur = it & 1;
        if (it < 15) {                       // prefetch next stage; drained at the barrier
            const int kn = (it + 1) * 32;
            bf16_t* dA = smem + (cur ^ 1) * 4096;
            bf16_t* dB = smem + 8192 + (cur ^ 1) * 4096;
            GLDS(gA + r0s * 512 + kn + kcs, dA + tid * 8);
            GLDS(gA + (64 + r0s) * 512 + kn + kcs, dA + (256 + tid) * 8);
            GLDS(gB + r0s * 512 + kn + kcs, dB + tid * 8);
            GLDS(gB + (64 + r0s) * 512 + kn + kcs, dB + (256 + tid) * 8);
        }
        const bf16_t* cA = smem + cur * 4096;
        const bf16_t* cB = smem + 8192 + cur * 4096;
        bf16x8 af[4], bfr[4];
        #pragma unroll
        for (int i = 0; i < 4; ++i) {
            af[i] = *(const bf16x8*)&cA[(wm + i * 16 + lrow) * 32 + quad * 8];
            bfr[i] = *(const bf16x8*)&cB[(wn + i * 16 + lrow) * 32 + quad * 8];
        }
        #pragma unroll
        for (int i = 0; i < 4; ++i)
            #pragma unroll
            for (int j = 0; j < 4; ++j)
                acc[i][j] = __builtin_amdgcn_mfma_f32_16x16x32_bf16(af[i], bfr[j], acc[i][j], 0, 0, 0);
        __syncthreads();
    }

    // epilogue: gelu+bias+scale, LDS transpose to d-contiguous, coalesced 16B stores
    bf16_t* hTb = hT + (size_t)b * 2097152 + slot * 1024;
    float4 bb[4];
    #pragma unroll
    for (int i = 0; i < 4; ++i)
        bb[i] = *(const float4*)(b1 + e * 1024 + d0 + wm + i * 16 + quad * 4);

    for (int half = 0; half < 2; ++half) {   // 64 hw-rows per pass (LDS: 64x136 bf16)
        if (wn == half * 64) {
            #pragma unroll
            for (int i = 0; i < 4; ++i)
                #pragma unroll
                for (int j = 0; j < 4; ++j) {
                    const int hw_l = j * 16 + lrow;
                    const int d_l = wm + i * 16 + quad * 4;
                    f32x4 a = acc[i][j];
                    bf16x4 o = { (bf16_t)(gelu_fast(a[0] + bb[i].x) * s),
                                 (bf16_t)(gelu_fast(a[1] + bb[i].y) * s),
                                 (bf16_t)(gelu_fast(a[2] + bb[i].z) * s),
                                 (bf16_t)(gelu_fast(a[3] + bb[i].w) * s) };
                    *(bf16x4*)&smem[hw_l * 136 + d_l] = o;
                }
        }
        __syncthreads();
        #pragma unroll
        for (int q = 0; q < 4; ++q) {
            const int cid = q * 256 + tid;
            const int row = cid >> 4, c16 = cid & 15;
            bf16x8 v = *(const bf16x8*)&smem[row * 136 + c16 * 8];
            *(bf16x8*)(hTb + (size_t)(n0 + half * 64 + row) * 2048 + d0 + c16 * 8) = v;
        }
        __syncthreads();
    }
}

// ---------- 4. GEMM2: out = x + W2t(sel) @ hT + scaled b2; 64x64 tile, BK=64, dbuf ----------
__global__ __launch_bounds__(256, 5) void gemm2_kernel(
    const bf16_t* __restrict__ W2t, const bf16_t* __restrict__ hT,
    const float* __restrict__ b2, const int* __restrict__ tidx,
    const float* __restrict__ scale, const float* __restrict__ x,
    float* __restrict__ out) {
    __shared__ bf16_t smem[16384];   // 32KB: A stages @0/4096 (2 panels of 64x32), B @8192/12288
    const int bid = blockIdx.x;
    const int b = bid >> 7, rem = bid & 127;
    const int c0 = (rem >> 4) * 64, n0 = (rem & 15) * 64;
    const int e0 = tidx[b * 2], e1 = tidx[b * 2 + 1];
    const float s0 = scale[b * 2], s1 = scale[b * 2 + 1];
    const int tid = threadIdx.x;
    const int lane = tid & 63, wave = tid >> 6;
    const int wm = (wave & 1) * 32, wn = (wave >> 1) * 32;
    const int lrow = lane & 15, quad = lane >> 4;

    const bf16_t* hTb = hT + (size_t)b * 2097152 + (size_t)n0 * 2048;
    const bf16_t* A0 = W2t + (size_t)e0 * 524288 + (size_t)c0 * 1024;
    const bf16_t* A1 = W2t + (size_t)e1 * 524288 + (size_t)c0 * 1024;
    const int sr = tid >> 2, kcs = (tid & 3) * 8;

    f32x4 acc[2][2];
    #pragma unroll
    for (int i = 0; i < 2; ++i)
        #pragma unroll
        for (int j = 0; j < 2; ++j) acc[i][j] = (f32x4){0.f, 0.f, 0.f, 0.f};

    auto stage = [&](int st, int it) {
        const int k0 = it * 64;
        const bf16_t* gA = ((k0 < 1024) ? A0 : A1) + (size_t)sr * 1024 + (k0 & 1023);
        bf16_t* dA = smem + st * 4096;
        bf16_t* dB = smem + 8192 + st * 4096;
        GLDS(gA + kcs, dA + tid * 8);
        GLDS(gA + 32 + kcs, dA + 2048 + tid * 8);
        const bf16_t* gBp = hTb + (size_t)sr * 2048 + k0;
        GLDS(gBp + kcs, dB + tid * 8);
        GLDS(gBp + 32 + kcs, dB + 2048 + tid * 8);
    };

    stage(0, 0);
    __syncthreads();

    for (int it = 0; it < 32; ++it) {
        const int cur = it & 1;
        if (it < 31) stage(cur ^ 1, it + 1);
        const bf16_t* cA = smem + cur * 4096;
        const bf16_t* cB = smem + 8192 + cur * 4096;
        #pragma unroll
        for (int ks = 0; ks < 2; ++ks) {     // two 32-deep panels
            bf16x8 af[2], bfr[2];
            #pragma unroll
            for (int i = 0; i < 2; ++i) {
                af[i] = *(const bf16x8*)&cA[ks * 2048 + (wm + i * 16 + lrow) * 32 + quad * 8];
                bfr[i] = *(const bf16x8*)&cB[ks * 2048 + (wn + i * 16 + lrow) * 32 + quad * 8];
            }
            #pragma unroll
            for (int i = 0; i < 2; ++i)
                #pragma unroll
                for (int j = 0; j < 2; ++j)
                    acc[i][j] = __builtin_amdgcn_mfma_f32_16x16x32_bf16(af[i], bfr[j], acc[i][j], 0, 0, 0);
        }
        __syncthreads();
    }

    #pragma unroll
    for (int i = 0; i < 2; ++i) {
        const int c_l = c0 + wm + i * 16 + quad * 4;
        const float4 bA = *(const float4*)(b2 + e0 * 512 + c_l);
        const float4 bB = *(const float4*)(b2 + e1 * 512 + c_l);
        const float bias[4] = { s0 * bA.x + s1 * bB.x, s0 * bA.y + s1 * bB.y,
                                s0 * bA.z + s1 * bB.z, s0 * bA.w + s1 * bB.w };
        #pragma unroll
        for (int j = 0; j < 2; ++j) {
            const int hw = n0 + wn + j * 16 + lrow;
            #pragma unroll
            for (int r = 0; r < 4; ++r) {
                const size_t o = (size_t)(b * 512 + c_l + r) * 1024 + hw;
                out[o] = x[o] + acc[i][j][r] + bias[r];
            }
        }
    }
}

extern "C" void kernel_launch(void* const* d_in, const int* in_sizes, int n_in,
                              void* d_out, int out_size, void* d_ws, size_t ws_size,
                              hipStream_t stream) {
    const float* x    = (const float*)d_in[0];
    const float* kmod = (const float*)d_in[1];
    const float* Wg   = (const float*)d_in[2];
    const float* bg   = (const float*)d_in[3];
    const float* W1   = (const float*)d_in[4];
    const float* b1   = (const float*)d_in[5];
    const float* W2   = (const float*)d_in[6];
    const float* b2   = (const float*)d_in[7];
    float* out = (float*)d_out;

    char* ws = (char*)d_ws;
    float* msum = (float*)ws;
    float* scl  = (float*)(ws + 16384);
    int*   tix  = (int*)(ws + 16448);
    bf16_t* xT  = (bf16_t*)(ws + 32768);
    bf16_t* W1t = (bf16_t*)(ws + 32768 + (size_t)8388608);
    bf16_t* W2t = (bf16_t*)(ws + 32768 + (size_t)2 * 8388608);
    bf16_t* hT  = (bf16_t*)(ws + 32768 + (size_t)3 * 8388608);

    hipMemsetAsync(msum, 0, 8 * 512 * sizeof(float), stream);
    transpose_cvt_all<<<12288, 256, 0, stream>>>(x, W1, W2, xT, W1t, W2t, msum);
    gate_kernel<<<1, 512, 0, stream>>>(msum, Wg, bg, kmod, tix, scl);
    gemm1_kernel<<<1024, 256, 0, stream>>>(W1t, xT, b1, tix, scl, hT);
    gemm2_kernel<<<1024, 256, 0, stream>>>(W2t, hT, b2, tix, scl, x, out);
}